// Round 3
// baseline (2888.573 us; speedup 1.0000x reference)
//
#include <hip/hip_runtime.h>
#include <stdint.h>

#define Dm 2048
#define Hn 16
#define HDm 128
#define FFm 8192
#define Bm 4
#define Sm 2048
#define Km 1024

typedef __attribute__((ext_vector_type(4))) float f32x4;
typedef __attribute__((ext_vector_type(8))) short s16x8;
typedef unsigned short u16;
typedef unsigned int u32;

__device__ __forceinline__ float bf_lo(u32 u){ u32 x = u << 16; return __builtin_bit_cast(float, x); }
__device__ __forceinline__ float bf_hi(u32 u){ u32 x = u & 0xffff0000u; return __builtin_bit_cast(float, x); }
__device__ __forceinline__ float bfu(u16 u){ u32 x = ((u32)u) << 16; return __builtin_bit_cast(float, x); }
__device__ __forceinline__ u16 f2bf(float f){
  u32 u = __builtin_bit_cast(u32, f);
  u += 0x7fffu + ((u >> 16) & 1u);
  return (u16)(u >> 16);
}
__device__ __forceinline__ u32 pack2(float a, float b){
  return (u32)f2bf(a) | ((u32)f2bf(b) << 16);
}
__device__ __forceinline__ void unpack8(uint4 a, float* f){
  f[0]=bf_lo(a.x); f[1]=bf_hi(a.x); f[2]=bf_lo(a.y); f[3]=bf_hi(a.y);
  f[4]=bf_lo(a.z); f[5]=bf_hi(a.z); f[6]=bf_lo(a.w); f[7]=bf_hi(a.w);
}
__device__ __forceinline__ uint4 pack8(const float* f){
  uint4 o; o.x=pack2(f[0],f[1]); o.y=pack2(f[2],f[3]); o.z=pack2(f[4],f[5]); o.w=pack2(f[6],f[7]); return o;
}
// load 8 consecutive logical elements from a raw input tensor (bf16 or fp32 per flag)
__device__ __forceinline__ void load8_in(const void* p, size_t off, int fp32, float* f){
  if (fp32){
    const float* pf = (const float*)p + off;
    float4 a = *(const float4*)pf;
    float4 b = *(const float4*)(pf + 4);
    f[0]=a.x; f[1]=a.y; f[2]=a.z; f[3]=a.w;
    f[4]=b.x; f[5]=b.y; f[6]=b.z; f[7]=b.w;
  } else {
    uint4 a = *(const uint4*)((const u16*)p + off);
    unpack8(a, f);
  }
}
__device__ __forceinline__ float gelu_f(float x){
  float t = tanhf(0.7978845608028654f*(x + 0.044715f*x*x*x));
  return 0.5f*x*(1.0f + t);
}
__device__ __forceinline__ float block_sum256(float s){
  #pragma unroll
  for (int off = 32; off; off >>= 1) s += __shfl_xor(s, off);
  __shared__ float red[4];
  int lane = threadIdx.x & 63, w = threadIdx.x >> 6;
  if (lane == 0) red[w] = s;
  __syncthreads();
  return red[0] + red[1] + red[2] + red[3];
}

// ---------------- dtype sniff: fp32 data read as bf16 pairs has insane low-halves ----------------
__global__ __launch_bounds__(256) void sniff_kernel(const u32* __restrict__ hs, int* __restrict__ flag){
  __shared__ int s;
  if (threadIdx.x == 0) s = 0;
  __syncthreads();
  int bad = 0;
  for (int i = threadIdx.x; i < 4096; i += 256){
    u32 w = hs[i];
    float lo = bf_lo(w), hi = bf_hi(w);
    if (!(fabsf(lo) < 1000.f && fabsf(hi) < 1000.f)) bad = 1;  // NaN or huge -> fp32 data
  }
  if (bad) atomicOr(&s, 1);
  __syncthreads();
  if (threadIdx.x == 0) flag[0] = s;
}

// ---------------- router: logits -> sigmoid weights, init selmap=-1 ----------------
__global__ __launch_bounds__(256) void router_kernel(const void* __restrict__ hs, const void* __restrict__ rw,
                                                     const int* __restrict__ dflag,
                                                     float* __restrict__ weights, int* __restrict__ selmap){
  int fp32 = *dflag;
  int row = blockIdx.x, t = threadIdx.x;
  float a[8], b8[8];
  load8_in(hs, (size_t)row*Dm + t*8, fp32, a);
  load8_in(rw, (size_t)t*8, fp32, b8);
  float s = 0.f;
  #pragma unroll
  for (int i = 0; i < 8; i++) s += a[i]*b8[i];
  float tot = block_sum256(s);
  if (t == 0){
    weights[row] = 1.0f/(1.0f + expf(-tot));
    selmap[row] = -1;
  }
}

// ---------------- exact top-K per batch: bitonic (w desc, idx asc), then idx asc ----------------
__global__ __launch_bounds__(1024) void topk_kernel(const float* __restrict__ weights, const int* __restrict__ position_ids,
                                                    int* __restrict__ idx, int* __restrict__ pos, int* __restrict__ selmap){
  int b = blockIdx.x, t = threadIdx.x;
  __shared__ float v[Sm];
  __shared__ int id[Sm];
  v[t] = weights[b*Sm + t];             id[t] = t;
  v[t+1024] = weights[b*Sm + t + 1024]; id[t+1024] = t + 1024;
  for (int size = 2; size <= Sm; size <<= 1){
    for (int stride = size >> 1; stride > 0; stride >>= 1){
      __syncthreads();
      int lo = ((t & ~(stride-1)) << 1) | (t & (stride-1));
      int hi = lo + stride;
      bool up = (lo & size) == 0;
      float va = v[lo], vb = v[hi]; int ia = id[lo], ib = id[hi];
      bool aFirst = (va > vb) || (va == vb && ia < ib);
      if (up ? !aFirst : aFirst){ v[lo]=vb; v[hi]=va; id[lo]=ib; id[hi]=ia; }
    }
  }
  __syncthreads();
  for (int size = 2; size <= Km; size <<= 1){
    for (int stride = size >> 1; stride > 0; stride >>= 1){
      __syncthreads();
      if (t < Km/2){
        int lo = ((t & ~(stride-1)) << 1) | (t & (stride-1));
        int hi = lo + stride;
        bool up = (lo & size) == 0;
        int ia = id[lo], ib = id[hi];
        bool aFirst = ia < ib;
        if (up ? !aFirst : aFirst){ id[lo]=ib; id[hi]=ia; }
      }
    }
  }
  __syncthreads();
  if (t < Km){
    int iv = id[t];
    idx[b*Km + t] = iv;
    pos[b*Km + t] = position_ids[iv];
    selmap[b*Sm + iv] = t;
  }
}

// ---------------- gather kept rows + rmsnorm*ln1 -> h1 (bf16) ----------------
__global__ __launch_bounds__(256) void gather_rmsnorm(const void* __restrict__ hs, const int* __restrict__ idx,
                                                      const void* __restrict__ ln1, const int* __restrict__ dflag,
                                                      u16* __restrict__ h1){
  int fp32 = *dflag;
  int g = blockIdx.x, t = threadIdx.x;
  int b = g >> 10;
  int row = idx[g];
  float f[8];
  load8_in(hs, ((size_t)b*Sm + row)*Dm + t*8, fp32, f);
  float ss = 0.f;
  #pragma unroll
  for (int i = 0; i < 8; i++) ss += f[i]*f[i];
  float tot = block_sum256(ss);
  float scale = rsqrtf(tot * (1.0f/Dm) + 1e-6f);
  float lw[8];
  load8_in(ln1, (size_t)t*8, fp32, lw);
  float o[8];
  #pragma unroll
  for (int i = 0; i < 8; i++) o[i] = f[i]*scale*lw[i];
  ((uint4*)(h1 + (size_t)g*Dm))[t] = pack8(o);
}

// ---------------- h2n = rmsnorm(hidden[idx] + ao)*ln2 ----------------
__global__ __launch_bounds__(256) void h2norm_kernel(const void* __restrict__ hs, const int* __restrict__ idx,
                                                     const u16* __restrict__ ao, const void* __restrict__ ln2,
                                                     const int* __restrict__ dflag, u16* __restrict__ h2n){
  int fp32 = *dflag;
  int g = blockIdx.x, t = threadIdx.x;
  int b = g >> 10;
  int row = idx[g];
  float ke[8], av[8];
  load8_in(hs, ((size_t)b*Sm + row)*Dm + t*8, fp32, ke);
  unpack8(((const uint4*)(ao + (size_t)g*Dm))[t], av);
  float f[8]; float ss = 0.f;
  #pragma unroll
  for (int i = 0; i < 8; i++){ f[i] = ke[i] + av[i]; ss += f[i]*f[i]; }
  float tot = block_sum256(ss);
  float scale = rsqrtf(tot * (1.0f/Dm) + 1e-6f);
  float lw[8];
  load8_in(ln2, (size_t)t*8, fp32, lw);
  float o[8];
  #pragma unroll
  for (int i = 0; i < 8; i++) o[i] = f[i]*scale*lw[i];
  ((uint4*)(h2n + (size_t)g*Dm))[t] = pack8(o);
}

// ---------------- transpose raw weight (bf16 or fp32) -> bf16 dst[C][R] = src[R][C] ----------------
__global__ __launch_bounds__(256) void transpose_k(const void* __restrict__ src, const int* __restrict__ dflag,
                                                   u16* __restrict__ dst, int R, int C, int ldS, size_t srcOff){
  int fp32 = *dflag;
  __shared__ u16 tile[64][72];
  int c0 = blockIdx.x << 6, r0 = blockIdx.y << 6;
  int t = threadIdx.x;
  int rr = t >> 3, cc = (t & 7) * 8;
  #pragma unroll
  for (int p = 0; p < 2; p++){
    float f[8];
    load8_in(src, srcOff + (size_t)(r0 + rr + p*32) * ldS + c0 + cc, fp32, f);
    u16 tmp[8];
    #pragma unroll
    for (int j = 0; j < 8; j++) tmp[j] = f2bf(f[j]);
    *(uint4*)&tile[rr + p*32][cc] = *(const uint4*)tmp;
  }
  __syncthreads();
  int col = t >> 3, r8 = (t & 7) * 8;
  #pragma unroll
  for (int p = 0; p < 2; p++){
    u16 tmp[8];
    #pragma unroll
    for (int j = 0; j < 8; j++) tmp[j] = tile[r8 + j][col + p*32];
    *(uint4*)(dst + (size_t)(c0 + col + p*32) * R + r0 + r8) = *(const uint4*)tmp;
  }
}

// ---------------- MFMA GEMM: C[M,N] (+)= A[M,K] * BT[N,K]^T ; 128x128 tile, 16x16x32 bf16 ----------------
// register staging (no global_load_lds this round — correctness first)
__global__ __launch_bounds__(256) void gemm_bt(const u16* __restrict__ A, const u16* __restrict__ BT, u16* __restrict__ Cmat,
                                               int Kd, int lda, int ldb, int ldc, int do_gelu, int accum){
  __shared__ __align__(16) u16 As[128*32];
  __shared__ __align__(16) u16 Bs[128*32];
  const int m0 = blockIdx.x * 128;
  const int n0 = blockIdx.y * 128;
  const int t = threadIdx.x;
  const int lane = t & 63;
  const int wave = t >> 6;
  const int wr = wave >> 1, wc = wave & 1;
  const int l16 = lane & 15, quad = lane >> 4;

  f32x4 acc[4][4];
  f32x4 zero = {0.f, 0.f, 0.f, 0.f};
  #pragma unroll
  for (int i = 0; i < 4; i++)
    #pragma unroll
    for (int j = 0; j < 4; j++) acc[i][j] = zero;

  const int trow = t >> 2;
  const int tcol = (t & 3) * 8;
  const u16* ga0 = A  + (size_t)(m0 + trow) * lda + tcol;
  const u16* ga1 = ga0 + (size_t)64 * lda;
  const u16* gb0 = BT + (size_t)(n0 + trow) * ldb + tcol;
  const u16* gb1 = gb0 + (size_t)64 * ldb;
  u16* sA = As + trow*32 + tcol;
  u16* sB = Bs + trow*32 + tcol;

  for (int k0 = 0; k0 < Kd; k0 += 32){
    s16x8 va0 = *(const s16x8*)(ga0 + k0);
    s16x8 va1 = *(const s16x8*)(ga1 + k0);
    s16x8 vb0 = *(const s16x8*)(gb0 + k0);
    s16x8 vb1 = *(const s16x8*)(gb1 + k0);
    __syncthreads();
    *(s16x8*)(sA)        = va0;
    *(s16x8*)(sA + 2048) = va1;
    *(s16x8*)(sB)        = vb0;
    *(s16x8*)(sB + 2048) = vb1;
    __syncthreads();
    s16x8 af[4], bfv[4];
    #pragma unroll
    for (int i = 0; i < 4; i++){
      af[i]  = *(const s16x8*)(As + (wr*64 + i*16 + l16)*32 + quad*8);
      bfv[i] = *(const s16x8*)(Bs + (wc*64 + i*16 + l16)*32 + quad*8);
    }
    #pragma unroll
    for (int i = 0; i < 4; i++)
      #pragma unroll
      for (int j = 0; j < 4; j++)
        acc[i][j] = __builtin_amdgcn_mfma_f32_16x16x32_bf16(af[i], bfv[j], acc[i][j], 0, 0, 0);
  }

  #pragma unroll
  for (int i = 0; i < 4; i++){
    int rbase = m0 + wr*64 + i*16 + quad*4;
    #pragma unroll
    for (int j = 0; j < 4; j++){
      int col = n0 + wc*64 + j*16 + l16;
      #pragma unroll
      for (int r = 0; r < 4; r++){
        float val = acc[i][j][r];
        if (do_gelu) val = gelu_f(val);
        size_t off = (size_t)(rbase + r)*ldc + col;
        if (accum) val += bfu(Cmat[off]);
        Cmat[off] = f2bf(val);
      }
    }
  }
}

// ---------------- RoPE in-place on q and k; layout (B,K,H,HD) ----------------
__global__ __launch_bounds__(256) void rope_kernel(u16* __restrict__ q, u16* __restrict__ k, const int* __restrict__ pos){
  int tid = blockIdx.x*256 + threadIdx.x;
  int row = tid >> 6, d = tid & 63;
  float p = (float)pos[row >> 4];          // row = (b*K+kk)*H + h, H=16
  float freq = exp2f(-0.20762050593589063f * (float)d);  // 10000^(-d/64)
  float ang = p * freq;
  float cs = cosf(ang), sn = sinf(ang);
  size_t base = (size_t)row * HDm + d;
  float x1 = bfu(q[base]), x2 = bfu(q[base+64]);
  q[base]    = f2bf(x1*cs - x2*sn);
  q[base+64] = f2bf(x2*cs + x1*sn);
  x1 = bfu(k[base]); x2 = bfu(k[base+64]);
  k[base]    = f2bf(x1*cs - x2*sn);
  k[base+64] = f2bf(x2*cs + x1*sn);
}

// ---------------- causal attention, online softmax, one wave per q-row ----------------
__global__ __launch_bounds__(256) void attn_kernel(const u16* __restrict__ q, const u16* __restrict__ k,
                                                   const u16* __restrict__ v, u16* __restrict__ o){
  int w = threadIdx.x >> 6, lane = threadIdx.x & 63;
  int g = blockIdx.x*4 + w;
  int b = g >> 14, h = (g >> 10) & 15, qi = g & 1023;
  size_t qoff = (((size_t)b*Km + qi)*Hn + h)*HDm;
  __shared__ float qs[4][HDm];
  u32 qu = *(const u32*)(q + qoff + 2*lane);
  const float scale = 0.08838834764831845f;  // 1/sqrt(128)
  qs[w][2*lane]   = bf_lo(qu)*scale;
  qs[w][2*lane+1] = bf_hi(qu)*scale;
  __syncthreads();
  float m = -INFINITY, l = 0.f, a0 = 0.f, a1 = 0.f;
  int nch = (qi >> 6) + 1;
  for (int c = 0; c < nch; c++){
    int j = (c << 6) + lane;
    bool valid = (j <= qi);
    float s = -INFINITY;
    if (valid){
      const uint4* kp = (const uint4*)(k + (((size_t)b*Km + j)*Hn + h)*HDm);
      float acc = 0.f;
      #pragma unroll
      for (int d8 = 0; d8 < 16; d8++){
        uint4 kv = kp[d8];
        const float* qq = &qs[w][d8*8];
        acc += bf_lo(kv.x)*qq[0] + bf_hi(kv.x)*qq[1]
             + bf_lo(kv.y)*qq[2] + bf_hi(kv.y)*qq[3]
             + bf_lo(kv.z)*qq[4] + bf_hi(kv.z)*qq[5]
             + bf_lo(kv.w)*qq[6] + bf_hi(kv.w)*qq[7];
      }
      s = acc;
    }
    float cm = s;
    #pragma unroll
    for (int off = 32; off; off >>= 1) cm = fmaxf(cm, __shfl_xor(cm, off));
    float mn = fmaxf(m, cm);
    float alpha = (m == -INFINITY) ? 0.f : expf(m - mn);
    float p = valid ? expf(s - mn) : 0.f;
    float ps = p;
    #pragma unroll
    for (int off = 32; off; off >>= 1) ps += __shfl_xor(ps, off);
    l = l*alpha + ps;
    a0 *= alpha; a1 *= alpha;
    int jmax = qi - (c << 6); if (jmax > 63) jmax = 63;
    const u16* vb = v + (((size_t)b*Km + (c << 6))*Hn + h)*HDm + 2*lane;
    for (int jj = 0; jj <= jmax; jj++){
      float pj = __shfl(p, jj);
      u32 vv = *(const u32*)(vb + (size_t)jj * (Hn*HDm));
      a0 += pj * bf_lo(vv);
      a1 += pj * bf_hi(vv);
    }
    m = mn;
  }
  float inv = 1.0f / l;
  *(u32*)(o + qoff + 2*lane) = pack2(a0*inv, a1*inv);
}

// ---------------- final compose/scatter ----------------
__global__ __launch_bounds__(256) void final_kernel(const void* __restrict__ hidden, const float* __restrict__ weights,
                                                    const int* __restrict__ selmap, const u16* __restrict__ delta,
                                                    const int* __restrict__ dflag, void* __restrict__ outv){
  int fp32 = *dflag;
  int row = blockIdx.x, t = threadIdx.x;
  int b = row >> 11;
  float w = weights[row];
  int sel = selmap[row];
  float hv[8];
  load8_in(hidden, (size_t)row*Dm + t*8, fp32, hv);
  float f[8];
  if (sel >= 0){
    size_t ko = ((size_t)(b*Km + sel))*Dm;
    float dv[8];
    unpack8(((const uint4*)(delta+ko))[t], dv);
    #pragma unroll
    for (int i = 0; i < 8; i++) f[i] = dv[i]*w + hv[i];
  } else {
    #pragma unroll
    for (int i = 0; i < 8; i++) f[i] = hv[i]*w;
  }
  if (fp32){
    float* o = (float*)outv + (size_t)row*Dm + t*8;
    float4 x; x.x=f[0]; x.y=f[1]; x.z=f[2]; x.w=f[3];
    float4 y; y.x=f[4]; y.y=f[5]; y.z=f[6]; y.w=f[7];
    *(float4*)o = x; *(float4*)(o+4) = y;
  } else {
    ((uint4*)((u16*)outv + (size_t)row*Dm))[t] = pack8(f);
  }
}

extern "C" void kernel_launch(void* const* d_in, const int* in_sizes, int n_in,
                              void* d_out, int out_size, void* d_ws, size_t ws_size,
                              hipStream_t stream){
  (void)in_sizes; (void)n_in; (void)out_size; (void)ws_size;
  const void* hidden      = d_in[0];
  const int* position_ids = (const int*)d_in[1];
  // d_in[2], d_in[3]: masks — constant all-True, unused by the math
  const void* router_w = d_in[4];
  const void* ln1 = d_in[5];
  const void* ln2 = d_in[6];
  const void* Wq  = d_in[7];
  const void* Wk  = d_in[8];
  const void* Wv  = d_in[9];
  const void* Wo  = d_in[10];
  const void* W1  = d_in[11];
  const void* W2  = d_in[12];
  char* ws = (char*)d_ws;
  const size_t MB = 1ull << 20;
  // workspace map (57 MiB total):
  float* weights = (float*)ws;              // 32 KB
  int* idx     = (int*)(ws + 32768);        // 16 KB
  int* pos     = (int*)(ws + 49152);        // 16 KB
  int* selmap  = (int*)(ws + 65536);        // 32 KB
  int* dflag   = (int*)(ws + 98304);        // 4 B
  u16* bufB = (u16*)(ws +  1*MB);           // 16 MB  h1 -> attn_out -> h2n
  u16* qb   = (u16*)(ws + 17*MB);           // 16 MB  q; reused as delta (aoB) after attn
  u16* kb   = (u16*)(ws + 33*MB);           // 16 MB
  u16* TW   = (u16*)(ws + 49*MB);           // 8 MB   transposed-weight scratch [2048][2048]
  u16* aoB  = qb;                           // alias: q dead after attn
  // d_out as scratch: v in bytes [0,16MB), gelu chunk in [16MB,32MB) — final overwrites all
  u16* vb   = (u16*)d_out;
  u16* gbuf = (u16*)d_out + 8ull*MB;        // 8M u16 = 16 MB offset

  sniff_kernel<<<1, 256, 0, stream>>>((const u32*)hidden, dflag);
  router_kernel<<<Bm*Sm, 256, 0, stream>>>(hidden, router_w, dflag, weights, selmap);
  topk_kernel<<<Bm, 1024, 0, stream>>>(weights, position_ids, idx, pos, selmap);
  gather_rmsnorm<<<Bm*Km, 256, 0, stream>>>(hidden, idx, ln1, dflag, bufB);

  transpose_k<<<dim3(32,32), 256, 0, stream>>>(Wq, dflag, TW, Dm, Dm, Dm, 0);
  gemm_bt<<<dim3(32,16), 256, 0, stream>>>(bufB, TW, qb, Dm, Dm, Dm, Dm, 0, 0);
  transpose_k<<<dim3(32,32), 256, 0, stream>>>(Wk, dflag, TW, Dm, Dm, Dm, 0);
  gemm_bt<<<dim3(32,16), 256, 0, stream>>>(bufB, TW, kb, Dm, Dm, Dm, Dm, 0, 0);
  transpose_k<<<dim3(32,32), 256, 0, stream>>>(Wv, dflag, TW, Dm, Dm, Dm, 0);
  gemm_bt<<<dim3(32,16), 256, 0, stream>>>(bufB, TW, vb, Dm, Dm, Dm, Dm, 0, 0);

  rope_kernel<<<16384, 256, 0, stream>>>(qb, kb, pos);
  attn_kernel<<<16384, 256, 0, stream>>>(qb, kb, vb, bufB);

  // Wo: reads bufB (attn out), writes aoB (=qb region, q now dead)
  transpose_k<<<dim3(32,32), 256, 0, stream>>>(Wo, dflag, TW, Dm, Dm, Dm, 0);
  gemm_bt<<<dim3(32,16), 256, 0, stream>>>(bufB, TW, aoB, Dm, Dm, Dm, Dm, 0, 0);

  h2norm_kernel<<<Bm*Km, 256, 0, stream>>>(hidden, idx, aoB, ln2, dflag, bufB);

  // MLP in 4 FF-chunks of 2048; gelu chunk [4096][2048] in d_out; accumulate into aoB
  for (int c = 0; c < 4; c++){
    transpose_k<<<dim3(32,32), 256, 0, stream>>>(W1, dflag, TW, Dm, 2048, FFm, (size_t)c*2048);
    gemm_bt<<<dim3(32,16), 256, 0, stream>>>(bufB, TW, gbuf, Dm, Dm, Dm, 2048, 1, 0);
    transpose_k<<<dim3(32,32), 256, 0, stream>>>(W2, dflag, TW, 2048, Dm, Dm, (size_t)c*2048*Dm);
    gemm_bt<<<dim3(32,16), 256, 0, stream>>>(gbuf, TW, aoB, 2048, 2048, 2048, Dm, 0, 1);
  }

  final_kernel<<<Bm*Sm, 256, 0, stream>>>(hidden, weights, selmap, aoB, dflag, d_out);
}